// Round 1
// baseline (710.576 us; speedup 1.0000x reference)
//
#include <hip/hip_runtime.h>
#include <hip/hip_bf16.h>
#include <stdint.h>

#define NN 100000   // nodes
#define NE 800000   // edges
#define ND 256      // dim (vocab = node_dim = hidden = 256)
#define NM 10000    // masked outputs

__device__ __forceinline__ float bf2f(unsigned short u) {
    return __uint_as_float(((unsigned)u) << 16);
}

// ---- degree count (edges only; +1 self-loop added in k_dinv) ----
__global__ void k_deg(const int* __restrict__ dst, int* __restrict__ cnt) {
    int e = blockIdx.x * 256 + threadIdx.x;
    if (e < NE) atomicAdd(&cnt[dst[e]], 1);
}

__global__ void k_dinv(const int* __restrict__ cnt, float* __restrict__ dinv) {
    int i = blockIdx.x * 256 + threadIdx.x;
    if (i < NN) dinv[i] = rsqrtf((float)cnt[i] + 1.0f);
}

__global__ void k_maskmap(const int* __restrict__ mpos, int* __restrict__ mask_map) {
    int j = blockIdx.x * 256 + threadIdx.x;
    if (j < NM) mask_map[mpos[j]] = j;   // duplicates: any winner is fine (rows identical)
}

// ---- layer-1 aggregation in one-hot (vocab) space: scalar atomics ----
__global__ void k_scatter1(const int* __restrict__ src, const int* __restrict__ dst,
                           const int* __restrict__ x, const float* __restrict__ dinv,
                           float* __restrict__ agg1) {
    int idx = blockIdx.x * 256 + threadIdx.x;
    if (idx < NE) {
        int s = src[idx], d = dst[idx];
        atomicAdd(&agg1[(size_t)d * ND + x[s]], dinv[s]);
    } else if (idx < NE + NN) {
        int i = idx - NE;                 // self loop
        atomicAdd(&agg1[(size_t)i * ND + x[i]], dinv[i]);
    }
}

// ---- M1 = emb @ W1, stored bf16 (256x256) ----
__global__ void k_m1(const float* __restrict__ emb, const float* __restrict__ W1,
                     unsigned short* __restrict__ M1) {
    __shared__ float er[ND];
    int v = blockIdx.x, c = threadIdx.x;
    er[c] = emb[v * ND + c];
    __syncthreads();
    float acc = 0.f;
    for (int k = 0; k < ND; k++) acc += er[k] * W1[k * ND + c];
    unsigned u = __float_as_uint(acc);
    u += 0x7fffu + ((u >> 16) & 1u);      // RNE to bf16
    M1[v * ND + c] = (unsigned short)(u >> 16);
}

// ---- h1 = relu(dinv * (agg1 @ M1) + b1); h1 may alias agg1 (in-place per row) ----
__global__ void k_expand(const float* agg1, float* h1,
                         const float* __restrict__ dinv,
                         const unsigned short* __restrict__ M1,
                         const float* __restrict__ b1) {
    int lane = threadIdx.x & 63;
    int wave = (blockIdx.x * blockDim.x + threadIdx.x) >> 6;
    int nw = (gridDim.x * blockDim.x) >> 6;
    float4 b1v = ((const float4*)b1)[lane];
    for (int i = wave; i < NN; i += nw) {
        float4 vals = ((const float4*)(agg1 + (size_t)i * ND))[lane];
        float a0 = 0.f, a1 = 0.f, a2 = 0.f, a3 = 0.f;
        float vj[4] = {vals.x, vals.y, vals.z, vals.w};
#pragma unroll
        for (int j = 0; j < 4; j++) {
            unsigned long long m = __ballot(vj[j] != 0.0f);
            while (m) {
                int sl = __ffsll(m) - 1;
                m &= m - 1;
                float w = __shfl(vj[j], sl);
                int v = sl * 4 + j;
                ushort4 mm = *(const ushort4*)(M1 + v * ND + lane * 4);
                a0 += w * bf2f(mm.x);
                a1 += w * bf2f(mm.y);
                a2 += w * bf2f(mm.z);
                a3 += w * bf2f(mm.w);
            }
        }
        float dv = dinv[i];
        float4 o;
        o.x = fmaxf(fmaf(dv, a0, b1v.x), 0.f);
        o.y = fmaxf(fmaf(dv, a1, b1v.y), 0.f);
        o.z = fmaxf(fmaf(dv, a2, b1v.z), 0.f);
        o.w = fmaxf(fmaf(dv, a3, b1v.w), 0.f);
        ((float4*)(h1 + (size_t)i * ND))[lane] = o;
    }
}

// ---- compact list of edges whose dst is masked ----
__global__ void k_filter(const int* __restrict__ src, const int* __restrict__ dst,
                         const int* __restrict__ mask_map, int2* __restrict__ elist,
                         int* __restrict__ ctr) {
    int e = blockIdx.x * 256 + threadIdx.x;
    int r = -1, s = 0;
    if (e < NE) {
        int d = dst[e];
        r = mask_map[d];
        s = src[e];
    }
    unsigned long long m = __ballot(r >= 0);
    if (m == 0ull) return;
    int lane = threadIdx.x & 63;
    int leader = __ffsll(m) - 1;
    int base = 0;
    if (lane == leader) base = atomicAdd(ctr, __popcll(m));
    base = __shfl(base, leader);
    if (r >= 0) {
        int prefix = __popcll(m & ((1ull << lane) - 1ull));
        elist[base + prefix] = make_int2(s, r);
    }
}

// ---- layer-2 aggregation over masked edges: agg2[r] += dinv[s] * h1[s] ----
__global__ void k_agg2(const int2* __restrict__ elist, const int* __restrict__ ctr,
                       const float* __restrict__ h1, const float* __restrict__ dinv,
                       float* __restrict__ agg2) {
    int lane = threadIdx.x & 63;
    int wave = (blockIdx.x * blockDim.x + threadIdx.x) >> 6;
    int nw = (gridDim.x * blockDim.x) >> 6;
    int n = *ctr;
    for (int e = wave; e < n; e += nw) {
        int2 sr = elist[e];
        int s = sr.x, r = sr.y;
        float w = dinv[s];
        float4 hv = ((const float4*)(h1 + (size_t)s * ND))[lane];
        float* ap = agg2 + (size_t)r * ND + lane * 4;
        atomicAdd(ap + 0, w * hv.x);
        atomicAdd(ap + 1, w * hv.y);
        atomicAdd(ap + 2, w * hv.z);
        atomicAdd(ap + 3, w * hv.w);
    }
}

// ---- out[j] = log_softmax(dinv[p]*( (agg2[r] + dinv[p]*h1[p]) @ W2 ) + b2) ----
__global__ __launch_bounds__(256) void k_out(
    const int* __restrict__ mpos, const int* __restrict__ mask_map,
    const float* __restrict__ dinv, const float* __restrict__ h1,
    const float* __restrict__ agg2, const float* __restrict__ W2,
    const float* __restrict__ b2, float* __restrict__ out) {
    __shared__ float vbuf[16][260];
    __shared__ float dvs[16];
    int t = threadIdx.x;
    int j0 = blockIdx.x * 16;
    for (int r = 0; r < 16; r++) {
        int j = j0 + r;
        int p = mpos[j];
        int rr = mask_map[p];
        float dv = dinv[p];
        vbuf[r][t] = agg2[(size_t)rr * ND + t] + h1[(size_t)p * ND + t] * dv;
        if (t == 0) dvs[r] = dv;
    }
    __syncthreads();
    int cq = (t & 63) * 4;   // 4 columns per lane
    int rg = t >> 6;         // wave id -> rows rg*4 .. rg*4+3
    float acc[4][4] = {};
    for (int k = 0; k < ND; k += 4) {
        float4 w0 = *(const float4*)&W2[(size_t)(k + 0) * ND + cq];
        float4 w1 = *(const float4*)&W2[(size_t)(k + 1) * ND + cq];
        float4 w2 = *(const float4*)&W2[(size_t)(k + 2) * ND + cq];
        float4 w3 = *(const float4*)&W2[(size_t)(k + 3) * ND + cq];
#pragma unroll
        for (int q = 0; q < 4; q++) {
            float4 v = *(const float4*)&vbuf[rg * 4 + q][k];
            acc[q][0] += v.x * w0.x + v.y * w1.x + v.z * w2.x + v.w * w3.x;
            acc[q][1] += v.x * w0.y + v.y * w1.y + v.z * w2.y + v.w * w3.y;
            acc[q][2] += v.x * w0.z + v.y * w1.z + v.z * w2.z + v.w * w3.z;
            acc[q][3] += v.x * w0.w + v.y * w1.w + v.z * w2.w + v.w * w3.w;
        }
    }
    float4 b2v = *(const float4*)&b2[cq];
#pragma unroll
    for (int q = 0; q < 4; q++) {
        int r = rg * 4 + q;
        float dv = dvs[r];
        float l0 = fmaf(dv, acc[q][0], b2v.x);
        float l1 = fmaf(dv, acc[q][1], b2v.y);
        float l2 = fmaf(dv, acc[q][2], b2v.z);
        float l3 = fmaf(dv, acc[q][3], b2v.w);
        float mx = fmaxf(fmaxf(l0, l1), fmaxf(l2, l3));
        for (int o = 32; o >= 1; o >>= 1) mx = fmaxf(mx, __shfl_xor(mx, o, 64));
        float s = __expf(l0 - mx) + __expf(l1 - mx) + __expf(l2 - mx) + __expf(l3 - mx);
        for (int o = 32; o >= 1; o >>= 1) s += __shfl_xor(s, o, 64);
        float lse = mx + __logf(s);
        float4 ov;
        ov.x = l0 - lse; ov.y = l1 - lse; ov.z = l2 - lse; ov.w = l3 - lse;
        *(float4*)&out[(size_t)(j0 + r) * ND + cq] = ov;
    }
}

extern "C" void kernel_launch(void* const* d_in, const int* in_sizes, int n_in,
                              void* d_out, int out_size, void* d_ws, size_t ws_size,
                              hipStream_t stream) {
    const int* x    = (const int*)d_in[0];
    const int* ei   = (const int*)d_in[1];
    const int* src  = ei;
    const int* dst  = ei + NE;
    const int* mpos = (const int*)d_in[2];
    const float* emb = (const float*)d_in[3];
    const float* W1  = (const float*)d_in[4];
    const float* b1  = (const float*)d_in[5];
    const float* W2  = (const float*)d_in[6];
    const float* b2  = (const float*)d_in[7];
    float* out = (float*)d_out;

    char* w = (char*)d_ws;
    size_t o = 0;
    int*   cnt      = (int*)(w + o);   o += (size_t)NN * 4;            // 400000
    float* dinv     = (float*)(w + o); o += (size_t)NN * 4;            // 400000
    int*   mask_map = (int*)(w + o);   o += (size_t)NN * 4;            // 400000
    int*   ctr      = (int*)(w + o);   o += 16;
    unsigned short* M1 = (unsigned short*)(w + o); o += (size_t)ND * ND * 2; // 131072
    int2*  elist    = (int2*)(w + o);  o += (size_t)NE * 8;            // 6.4 MB
    float* agg2     = (float*)(w + o); o += (size_t)NM * ND * 4;       // 10.24 MB
    float* agg1     = (float*)(w + o); o += (size_t)NN * ND * 4;       // 102.4 MB
    float* h1       = agg1;  // in-place: each wave fully reads its row before writing it

    hipMemsetAsync(cnt, 0, (size_t)NN * 4, stream);
    hipMemsetAsync(mask_map, 0xFF, (size_t)NN * 4, stream);  // -1
    hipMemsetAsync(ctr, 0, 4, stream);
    hipMemsetAsync(agg1, 0, (size_t)NN * ND * 4, stream);
    hipMemsetAsync(agg2, 0, (size_t)NM * ND * 4, stream);

    k_deg<<<(NE + 255) / 256, 256, 0, stream>>>(dst, cnt);
    k_dinv<<<(NN + 255) / 256, 256, 0, stream>>>(cnt, dinv);
    k_maskmap<<<(NM + 255) / 256, 256, 0, stream>>>(mpos, mask_map);
    k_scatter1<<<(NE + NN + 255) / 256, 256, 0, stream>>>(src, dst, x, dinv, agg1);
    k_m1<<<ND, ND, 0, stream>>>(emb, W1, M1);
    k_expand<<<2048, 256, 0, stream>>>(agg1, h1, dinv, M1, b1);
    k_filter<<<(NE + 255) / 256, 256, 0, stream>>>(src, dst, mask_map, elist, ctr);
    k_agg2<<<1024, 256, 0, stream>>>(elist, ctr, h1, dinv, agg2);
    k_out<<<NM / 16, 256, 0, stream>>>(mpos, mask_map, dinv, h1, agg2, W2, b2, out);
}

// Round 2
// 352.153 us; speedup vs baseline: 2.0178x; 2.0178x over previous
//
#include <hip/hip_runtime.h>
#include <hip/hip_bf16.h>
#include <stdint.h>

#define NN 100000   // nodes
#define NE 800000   // edges
#define ND 256      // dim (vocab = node_dim = hidden = 256)
#define NM 10000    // masked outputs
#define CAP2 262144 // capacity for masked-edge list (expected ~76k)

__device__ __forceinline__ float bf2f(unsigned short u) {
    return __uint_as_float(((unsigned)u) << 16);
}

// ---- in-degree count (self-loop added analytically in k_dinv) ----
__global__ void k_deg(const int* __restrict__ dst, int* __restrict__ cnt) {
    int e = blockIdx.x * 256 + threadIdx.x;
    if (e < NE) atomicAdd(&cnt[dst[e]], 1);
}

__global__ void k_dinv(const int* __restrict__ cnt, float* __restrict__ dinv) {
    int i = blockIdx.x * 256 + threadIdx.x;
    if (i < NN) dinv[i] = rsqrtf((float)cnt[i] + 1.0f);
}

__global__ void k_maskmap(const int* __restrict__ mpos, int* __restrict__ mask_map) {
    int j = blockIdx.x * 256 + threadIdx.x;
    if (j < NM) mask_map[mpos[j]] = j;   // duplicates: any winner (rows identical)
}

// ================= 3-phase exclusive scan (CSR offsets) =================
__global__ void k_scanA(const int* __restrict__ cnt, int* __restrict__ part, int n) {
    int b = blockIdx.x, t = threadIdx.x;
    int base = b * 1024 + t * 4;
    int s = 0;
#pragma unroll
    for (int k = 0; k < 4; k++) { int i = base + k; if (i < n) s += cnt[i]; }
    int lane = t & 63, wv = t >> 6;
    int x = s;
    for (int o = 1; o < 64; o <<= 1) { int y = __shfl_up(x, o, 64); if (lane >= o) x += y; }
    __shared__ int ws[4];
    if (lane == 63) ws[wv] = x;
    __syncthreads();
    if (t == 0) part[b] = ws[0] + ws[1] + ws[2] + ws[3];
}

__global__ void k_scanB(int* __restrict__ part, int nb) {
    if (threadIdx.x == 0 && blockIdx.x == 0) {
        int acc = 0;
        for (int i = 0; i < nb; i++) { int v = part[i]; part[i] = acc; acc += v; }
    }
}

__global__ void k_scanC(const int* __restrict__ cnt, const int* __restrict__ part,
                        int* __restrict__ off, int* __restrict__ cur, int n) {
    int b = blockIdx.x, t = threadIdx.x;
    int base = b * 1024 + t * 4;
    int v[4]; int s = 0;
#pragma unroll
    for (int k = 0; k < 4; k++) {
        int i = base + k;
        v[k] = (i < n) ? cnt[i] : 0;
        s += v[k];
    }
    int lane = t & 63, wv = t >> 6;
    int x = s;
    for (int o = 1; o < 64; o <<= 1) { int y = __shfl_up(x, o, 64); if (lane >= o) x += y; }
    __shared__ int ws[4];
    if (lane == 63) ws[wv] = x;
    __syncthreads();
    int add = part[b];
    for (int k = 0; k < wv; k++) add += ws[k];
    int run = add + x - s;   // exclusive prefix for this thread's first element
#pragma unroll
    for (int k = 0; k < 4; k++) {
        int i = base + k;
        if (i < n) { off[i] = run; cur[i] = run; }
        run += v[k];
    }
}

// ---- bucket-scatter layer-1 contributions: (vocab of src, dinv of src) ----
__global__ void k_scat1(const int* __restrict__ src, const int* __restrict__ dst,
                        const int* __restrict__ x, const float* __restrict__ dinv,
                        int* __restrict__ cur1, int2* __restrict__ pairs) {
    int e = blockIdx.x * 256 + threadIdx.x;
    if (e >= NE) return;
    int s = src[e], d = dst[e];
    int pos = atomicAdd(&cur1[d], 1);
    pairs[pos] = make_int2(x[s], __float_as_int(dinv[s]));
}

// ---- M1 = emb @ W1, stored bf16 (256x256, L2-resident) ----
__global__ void k_m1(const float* __restrict__ emb, const float* __restrict__ W1,
                     unsigned short* __restrict__ M1) {
    __shared__ float er[ND];
    int v = blockIdx.x, c = threadIdx.x;
    er[c] = emb[v * ND + c];
    __syncthreads();
    float acc = 0.f;
    for (int k = 0; k < ND; k++) acc += er[k] * W1[k * ND + c];
    unsigned u = __float_as_uint(acc);
    u += 0x7fffu + ((u >> 16) & 1u);      // RNE to bf16
    M1[v * ND + c] = (unsigned short)(u >> 16);
}

// ---- h1 = relu(dinv_i * (sum_e w_e * M1[v_e] + dinv_i * M1[x_i]) + b1) ----
__global__ void k_expand(const int* __restrict__ x, const float* __restrict__ dinv,
                         const int* __restrict__ off1, const int* __restrict__ cnt,
                         const int2* __restrict__ pairs,
                         const unsigned short* __restrict__ M1,
                         const float* __restrict__ b1, float* __restrict__ h1) {
    int lane = threadIdx.x & 63;
    int wave = (blockIdx.x * 256 + threadIdx.x) >> 6;
    if (wave >= NN) return;
    int i = wave;
    float4 b1v = ((const float4*)b1)[lane];
    // self-loop term
    int v0 = x[i];
    float w0 = dinv[i];
    ushort4 mm = *(const ushort4*)(M1 + (size_t)v0 * ND + lane * 4);
    float a0 = w0 * bf2f(mm.x), a1 = w0 * bf2f(mm.y);
    float a2 = w0 * bf2f(mm.z), a3 = w0 * bf2f(mm.w);
    int beg = off1[i], end = beg + cnt[i];
    for (int e = beg; e < end; e++) {
        int2 p = pairs[e];                 // wave-uniform load (broadcast)
        float w = __int_as_float(p.y);
        ushort4 m2 = *(const ushort4*)(M1 + (size_t)p.x * ND + lane * 4);
        a0 += w * bf2f(m2.x);
        a1 += w * bf2f(m2.y);
        a2 += w * bf2f(m2.z);
        a3 += w * bf2f(m2.w);
    }
    float dv = w0;
    float4 o;
    o.x = fmaxf(fmaf(dv, a0, b1v.x), 0.f);
    o.y = fmaxf(fmaf(dv, a1, b1v.y), 0.f);
    o.z = fmaxf(fmaf(dv, a2, b1v.z), 0.f);
    o.w = fmaxf(fmaf(dv, a3, b1v.w), 0.f);
    ((float4*)(h1 + (size_t)i * ND))[lane] = o;
}

// ---- count masked in-edges per representative row r ----
__global__ void k_cnt2(const int* __restrict__ dst, const int* __restrict__ mask_map,
                       int* __restrict__ cnt2) {
    int e = blockIdx.x * 256 + threadIdx.x;
    if (e < NE) {
        int r = mask_map[dst[e]];
        if (r >= 0) atomicAdd(&cnt2[r], 1);
    }
}

__global__ void k_scat2(const int* __restrict__ src, const int* __restrict__ dst,
                        const int* __restrict__ mask_map, int* __restrict__ cur2,
                        int* __restrict__ eidx2) {
    int e = blockIdx.x * 256 + threadIdx.x;
    if (e < NE) {
        int r = mask_map[dst[e]];
        if (r >= 0) {
            int pos = atomicAdd(&cur2[r], 1);
            eidx2[pos] = src[e];
        }
    }
}

// ---- layer-2 aggregation, CSR, register accumulate: agg2[r] = sum dinv[s]*h1[s] ----
__global__ void k_agg2(const int* __restrict__ eidx2, const int* __restrict__ off2,
                       const int* __restrict__ cnt2, const float* __restrict__ h1,
                       const float* __restrict__ dinv, float* __restrict__ agg2) {
    int lane = threadIdx.x & 63;
    int wave = (blockIdx.x * 256 + threadIdx.x) >> 6;
    if (wave >= NM) return;
    int r = wave;
    int beg = off2[r], end = beg + cnt2[r];
    float4 acc = make_float4(0.f, 0.f, 0.f, 0.f);
    for (int e = beg; e < end; e++) {
        int s = eidx2[e];                  // wave-uniform load
        float w = dinv[s];
        float4 hv = ((const float4*)(h1 + (size_t)s * ND))[lane];
        acc.x += w * hv.x;
        acc.y += w * hv.y;
        acc.z += w * hv.z;
        acc.w += w * hv.w;
    }
    ((float4*)(agg2 + (size_t)r * ND))[lane] = acc;
}

// ---- out[j] = log_softmax(dinv[p]*( (agg2[r] + dinv[p]*h1[p]) @ W2 ) + b2) ----
__global__ __launch_bounds__(256) void k_out(
    const int* __restrict__ mpos, const int* __restrict__ mask_map,
    const float* __restrict__ dinv, const float* __restrict__ h1,
    const float* __restrict__ agg2, const float* __restrict__ W2,
    const float* __restrict__ b2, float* __restrict__ out) {
    __shared__ float vbuf[16][260];
    __shared__ float dvs[16];
    int t = threadIdx.x;
    int j0 = blockIdx.x * 16;
    for (int r = 0; r < 16; r++) {
        int j = j0 + r;
        int p = mpos[j];
        int rr = mask_map[p];
        float dv = dinv[p];
        vbuf[r][t] = agg2[(size_t)rr * ND + t] + h1[(size_t)p * ND + t] * dv;
        if (t == 0) dvs[r] = dv;
    }
    __syncthreads();
    int cq = (t & 63) * 4;   // 4 columns per lane
    int rg = t >> 6;         // wave id -> rows rg*4 .. rg*4+3
    float acc[4][4] = {};
    for (int k = 0; k < ND; k += 4) {
        float4 w0 = *(const float4*)&W2[(size_t)(k + 0) * ND + cq];
        float4 w1 = *(const float4*)&W2[(size_t)(k + 1) * ND + cq];
        float4 w2 = *(const float4*)&W2[(size_t)(k + 2) * ND + cq];
        float4 w3 = *(const float4*)&W2[(size_t)(k + 3) * ND + cq];
#pragma unroll
        for (int q = 0; q < 4; q++) {
            float4 v = *(const float4*)&vbuf[rg * 4 + q][k];
            acc[q][0] += v.x * w0.x + v.y * w1.x + v.z * w2.x + v.w * w3.x;
            acc[q][1] += v.x * w0.y + v.y * w1.y + v.z * w2.y + v.w * w3.y;
            acc[q][2] += v.x * w0.z + v.y * w1.z + v.z * w2.z + v.w * w3.z;
            acc[q][3] += v.x * w0.w + v.y * w1.w + v.z * w2.w + v.w * w3.w;
        }
    }
    float4 b2v = *(const float4*)&b2[cq];
#pragma unroll
    for (int q = 0; q < 4; q++) {
        int r = rg * 4 + q;
        float dv = dvs[r];
        float l0 = fmaf(dv, acc[q][0], b2v.x);
        float l1 = fmaf(dv, acc[q][1], b2v.y);
        float l2 = fmaf(dv, acc[q][2], b2v.z);
        float l3 = fmaf(dv, acc[q][3], b2v.w);
        float mx = fmaxf(fmaxf(l0, l1), fmaxf(l2, l3));
        for (int o = 32; o >= 1; o >>= 1) mx = fmaxf(mx, __shfl_xor(mx, o, 64));
        float s = __expf(l0 - mx) + __expf(l1 - mx) + __expf(l2 - mx) + __expf(l3 - mx);
        for (int o = 32; o >= 1; o >>= 1) s += __shfl_xor(s, o, 64);
        float lse = mx + __logf(s);
        float4 ov;
        ov.x = l0 - lse; ov.y = l1 - lse; ov.z = l2 - lse; ov.w = l3 - lse;
        *(float4*)&out[(size_t)(j0 + r) * ND + cq] = ov;
    }
}

extern "C" void kernel_launch(void* const* d_in, const int* in_sizes, int n_in,
                              void* d_out, int out_size, void* d_ws, size_t ws_size,
                              hipStream_t stream) {
    const int* x    = (const int*)d_in[0];
    const int* ei   = (const int*)d_in[1];
    const int* src  = ei;
    const int* dst  = ei + NE;
    const int* mpos = (const int*)d_in[2];
    const float* emb = (const float*)d_in[3];
    const float* W1  = (const float*)d_in[4];
    const float* b1  = (const float*)d_in[5];
    const float* W2  = (const float*)d_in[6];
    const float* b2  = (const float*)d_in[7];
    float* out = (float*)d_out;

    char* w = (char*)d_ws;
    size_t o = 0;
    int*   cnt      = (int*)(w + o);   o += (size_t)NN * 4;
    float* dinv     = (float*)(w + o); o += (size_t)NN * 4;
    int*   mask_map = (int*)(w + o);   o += (size_t)NN * 4;
    int*   off1     = (int*)(w + o);   o += (size_t)NN * 4;
    int*   cur1     = (int*)(w + o);   o += (size_t)NN * 4;
    int*   cnt2     = (int*)(w + o);   o += (size_t)NM * 4;
    int*   off2     = (int*)(w + o);   o += (size_t)NM * 4;
    int*   cur2     = (int*)(w + o);   o += (size_t)NM * 4;
    int*   part     = (int*)(w + o);   o += 128 * 4;
    unsigned short* M1 = (unsigned short*)(w + o); o += (size_t)ND * ND * 2;
    int2*  pairs    = (int2*)(w + o);  o += (size_t)NE * 8;            // 6.4 MB
    int*   eidx2    = (int*)(w + o);   o += (size_t)CAP2 * 4;          // 1 MB
    float* agg2     = (float*)(w + o); o += (size_t)NM * ND * 4;       // 10.24 MB
    float* h1       = (float*)(w + o); o += (size_t)NN * ND * 4;       // 102.4 MB

    const int NB1 = (NN + 1023) / 1024;  // 98
    const int NB2 = (NM + 1023) / 1024;  // 10

    hipMemsetAsync(cnt, 0, (size_t)NN * 4, stream);
    hipMemsetAsync(cnt2, 0, (size_t)NM * 4, stream);
    hipMemsetAsync(mask_map, 0xFF, (size_t)NN * 4, stream);  // -1

    k_deg<<<(NE + 255) / 256, 256, 0, stream>>>(dst, cnt);
    k_dinv<<<(NN + 255) / 256, 256, 0, stream>>>(cnt, dinv);
    k_maskmap<<<(NM + 255) / 256, 256, 0, stream>>>(mpos, mask_map);

    // CSR over layer-1 destinations
    k_scanA<<<NB1, 256, 0, stream>>>(cnt, part, NN);
    k_scanB<<<1, 64, 0, stream>>>(part, NB1);
    k_scanC<<<NB1, 256, 0, stream>>>(cnt, part, off1, cur1, NN);
    k_scat1<<<(NE + 255) / 256, 256, 0, stream>>>(src, dst, x, dinv, cur1, pairs);

    k_m1<<<ND, ND, 0, stream>>>(emb, W1, M1);
    k_expand<<<NN / 4, 256, 0, stream>>>(x, dinv, off1, cnt, pairs, M1, b1, h1);

    // CSR over masked rows (layer 2)
    k_cnt2<<<(NE + 255) / 256, 256, 0, stream>>>(dst, mask_map, cnt2);
    k_scanA<<<NB2, 256, 0, stream>>>(cnt2, part, NM);
    k_scanB<<<1, 64, 0, stream>>>(part, NB2);
    k_scanC<<<NB2, 256, 0, stream>>>(cnt2, part, off2, cur2, NM);
    k_scat2<<<(NE + 255) / 256, 256, 0, stream>>>(src, dst, mask_map, cur2, eidx2);

    k_agg2<<<NM / 4, 256, 0, stream>>>(eidx2, off2, cnt2, h1, dinv, agg2);
    k_out<<<NM / 16, 256, 0, stream>>>(mpos, mask_map, dinv, h1, agg2, W2, b2, out);
}

// Round 3
// 302.722 us; speedup vs baseline: 2.3473x; 1.1633x over previous
//
#include <hip/hip_runtime.h>
#include <hip/hip_bf16.h>
#include <stdint.h>

#define NN 100000   // nodes
#define NE 800000   // edges
#define ND 256      // dim (vocab = node_dim = hidden = 256)
#define NM 10000    // masked outputs
#define CAP2 262144 // capacity for masked-edge list (expected ~76k)

__device__ __forceinline__ float bf2f(unsigned short u) {
    return __uint_as_float(((unsigned)u) << 16);
}
__device__ __forceinline__ unsigned short f2bf(float f) {
    unsigned u = __float_as_uint(f);
    u += 0x7fffu + ((u >> 16) & 1u);   // RNE
    return (unsigned short)(u >> 16);
}

// ---- mask map + flag masked positions as needed ----
__global__ void k_maskmap(const int* __restrict__ mpos, int* __restrict__ mask_map,
                          int* __restrict__ flag) {
    int j = blockIdx.x * 256 + threadIdx.x;
    if (j < NM) { int p = mpos[j]; mask_map[p] = j; flag[p] = 1; }
}

// ---- one edge pass: in-degree, masked-in-edge count, needed-source flag ----
__global__ void k_edge1(const int* __restrict__ src, const int* __restrict__ dst,
                        const int* __restrict__ mask_map,
                        int* __restrict__ cnt, int* __restrict__ cnt2,
                        int* __restrict__ flag) {
    int e = blockIdx.x * 256 + threadIdx.x;
    if (e >= NE) return;
    int d = dst[e];
    atomicAdd(&cnt[d], 1);
    int r = mask_map[d];
    if (r >= 0) {
        atomicAdd(&cnt2[r], 1);
        flag[src[e]] = 1;
    }
}

__global__ void k_dinv(const int* __restrict__ cnt, float* __restrict__ dinv) {
    int i = blockIdx.x * 256 + threadIdx.x;
    if (i < NN) dinv[i] = rsqrtf((float)cnt[i] + 1.0f);
}

// ---- compact needed nodes ----
__global__ void k_compact(const int* __restrict__ flag, int* __restrict__ nctr,
                          int* __restrict__ nlist, int* __restrict__ s2c) {
    int i = blockIdx.x * 256 + threadIdx.x;
    if (i < NN && flag[i]) {
        int c = atomicAdd(nctr, 1);
        nlist[c] = i;
        s2c[i] = c;
    }
}

// ================= 3-phase exclusive scan (CSR offsets) =================
__global__ void k_scanA(const int* __restrict__ cnt, int* __restrict__ part, int n) {
    int b = blockIdx.x, t = threadIdx.x;
    int base = b * 1024 + t * 4;
    int s = 0;
#pragma unroll
    for (int k = 0; k < 4; k++) { int i = base + k; if (i < n) s += cnt[i]; }
    int lane = t & 63, wv = t >> 6;
    int x = s;
    for (int o = 1; o < 64; o <<= 1) { int y = __shfl_up(x, o, 64); if (lane >= o) x += y; }
    __shared__ int ws[4];
    if (lane == 63) ws[wv] = x;
    __syncthreads();
    if (t == 0) part[b] = ws[0] + ws[1] + ws[2] + ws[3];
}

__global__ void k_scanB(int* __restrict__ part, int nb) {
    if (threadIdx.x == 0 && blockIdx.x == 0) {
        int acc = 0;
        for (int i = 0; i < nb; i++) { int v = part[i]; part[i] = acc; acc += v; }
    }
}

__global__ void k_scanC(const int* __restrict__ cnt, const int* __restrict__ part,
                        int* __restrict__ off, int* __restrict__ cur, int n) {
    int b = blockIdx.x, t = threadIdx.x;
    int base = b * 1024 + t * 4;
    int v[4]; int s = 0;
#pragma unroll
    for (int k = 0; k < 4; k++) {
        int i = base + k;
        v[k] = (i < n) ? cnt[i] : 0;
        s += v[k];
    }
    int lane = t & 63, wv = t >> 6;
    int x = s;
    for (int o = 1; o < 64; o <<= 1) { int y = __shfl_up(x, o, 64); if (lane >= o) x += y; }
    __shared__ int ws[4];
    if (lane == 63) ws[wv] = x;
    __syncthreads();
    int add = part[b];
    for (int k = 0; k < wv; k++) add += ws[k];
    int run = add + x - s;
#pragma unroll
    for (int k = 0; k < 4; k++) {
        int i = base + k;
        if (i < n) { off[i] = run; cur[i] = run; }
        run += v[k];
    }
}

// ---- merged scatter: layer-1 pairs (needed dst only) + layer-2 edge list ----
__global__ void k_scat(const int* __restrict__ src, const int* __restrict__ dst,
                       const int* __restrict__ x, const float* __restrict__ dinv,
                       const int* __restrict__ mask_map, const int* __restrict__ flag,
                       const int* __restrict__ s2c,
                       int* __restrict__ cur1, int2* __restrict__ pairs,
                       int* __restrict__ cur2, int2* __restrict__ elist2) {
    int e = blockIdx.x * 256 + threadIdx.x;
    if (e >= NE) return;
    int d = dst[e];
    int f = flag[d];
    int r = mask_map[d];
    if (f == 0 && r < 0) return;
    int s = src[e];
    float w = dinv[s];
    if (f) {
        int pos = atomicAdd(&cur1[d], 1);
        pairs[pos] = make_int2(x[s], __float_as_int(w));
    }
    if (r >= 0) {
        int pos2 = atomicAdd(&cur2[r], 1);
        elist2[pos2] = make_int2(s2c[s], __float_as_int(w));
    }
}

// ---- M1 = emb @ W1, stored bf16 (256x256, L2-resident) ----
__global__ void k_m1(const float* __restrict__ emb, const float* __restrict__ W1,
                     unsigned short* __restrict__ M1) {
    __shared__ float er[ND];
    int v = blockIdx.x, c = threadIdx.x;
    er[c] = emb[v * ND + c];
    __syncthreads();
    float acc = 0.f;
    for (int k = 0; k < ND; k++) acc += er[k] * W1[k * ND + c];
    M1[v * ND + c] = f2bf(acc);
}

// ---- h1c[c] = relu(dinv_i * (sum_e w_e*M1[v_e] + dinv_i*M1[x_i]) + b1), bf16 ----
__global__ void k_expand(const int* __restrict__ nctr, const int* __restrict__ nlist,
                         const int* __restrict__ x, const float* __restrict__ dinv,
                         const int* __restrict__ off1, const int* __restrict__ cnt,
                         const int2* __restrict__ pairs,
                         const unsigned short* __restrict__ M1,
                         const float* __restrict__ b1,
                         unsigned short* __restrict__ h1c) {
    int lane = threadIdx.x & 63;
    int wave = (blockIdx.x * 256 + threadIdx.x) >> 6;
    if (wave >= *nctr) return;
    int i = nlist[wave];
    float4 b1v = ((const float4*)b1)[lane];
    int v0 = x[i];
    float w0 = dinv[i];
    ushort4 mm = *(const ushort4*)(M1 + (size_t)v0 * ND + lane * 4);
    float a0 = w0 * bf2f(mm.x), a1 = w0 * bf2f(mm.y);
    float a2 = w0 * bf2f(mm.z), a3 = w0 * bf2f(mm.w);
    int e = off1[i], end = e + cnt[i];
    for (; e + 4 <= end; e += 4) {
        int2 pA = pairs[e + 0];
        int2 pB = pairs[e + 1];
        int2 pC = pairs[e + 2];
        int2 pD = pairs[e + 3];
        ushort4 mA = *(const ushort4*)(M1 + (size_t)pA.x * ND + lane * 4);
        ushort4 mB = *(const ushort4*)(M1 + (size_t)pB.x * ND + lane * 4);
        ushort4 mC = *(const ushort4*)(M1 + (size_t)pC.x * ND + lane * 4);
        ushort4 mD = *(const ushort4*)(M1 + (size_t)pD.x * ND + lane * 4);
        float wA = __int_as_float(pA.y), wB = __int_as_float(pB.y);
        float wC = __int_as_float(pC.y), wD = __int_as_float(pD.y);
        a0 += wA * bf2f(mA.x) + wB * bf2f(mB.x) + wC * bf2f(mC.x) + wD * bf2f(mD.x);
        a1 += wA * bf2f(mA.y) + wB * bf2f(mB.y) + wC * bf2f(mC.y) + wD * bf2f(mD.y);
        a2 += wA * bf2f(mA.z) + wB * bf2f(mB.z) + wC * bf2f(mC.z) + wD * bf2f(mD.z);
        a3 += wA * bf2f(mA.w) + wB * bf2f(mB.w) + wC * bf2f(mC.w) + wD * bf2f(mD.w);
    }
    for (; e < end; e++) {
        int2 p = pairs[e];
        float w = __int_as_float(p.y);
        ushort4 m2 = *(const ushort4*)(M1 + (size_t)p.x * ND + lane * 4);
        a0 += w * bf2f(m2.x);
        a1 += w * bf2f(m2.y);
        a2 += w * bf2f(m2.z);
        a3 += w * bf2f(m2.w);
    }
    ushort4 o;
    o.x = f2bf(fmaxf(fmaf(w0, a0, b1v.x), 0.f));
    o.y = f2bf(fmaxf(fmaf(w0, a1, b1v.y), 0.f));
    o.z = f2bf(fmaxf(fmaf(w0, a2, b1v.z), 0.f));
    o.w = f2bf(fmaxf(fmaf(w0, a3, b1v.w), 0.f));
    ((ushort4*)(h1c + (size_t)wave * ND))[lane] = o;
}

// ---- layer-2 aggregation (CSR, register acc): agg2[r] = sum w*h1c[cidx] ----
__global__ void k_agg2(const int2* __restrict__ elist2, const int* __restrict__ off2,
                       const int* __restrict__ cnt2,
                       const unsigned short* __restrict__ h1c,
                       float* __restrict__ agg2) {
    int lane = threadIdx.x & 63;
    int wave = (blockIdx.x * 256 + threadIdx.x) >> 6;
    if (wave >= NM) return;
    int r = wave;
    int e = off2[r], end = e + cnt2[r];
    float a0 = 0.f, a1 = 0.f, a2 = 0.f, a3 = 0.f;
    for (; e + 4 <= end; e += 4) {
        int2 pA = elist2[e + 0];
        int2 pB = elist2[e + 1];
        int2 pC = elist2[e + 2];
        int2 pD = elist2[e + 3];
        ushort4 hA = *(const ushort4*)(h1c + (size_t)pA.x * ND + lane * 4);
        ushort4 hB = *(const ushort4*)(h1c + (size_t)pB.x * ND + lane * 4);
        ushort4 hC = *(const ushort4*)(h1c + (size_t)pC.x * ND + lane * 4);
        ushort4 hD = *(const ushort4*)(h1c + (size_t)pD.x * ND + lane * 4);
        float wA = __int_as_float(pA.y), wB = __int_as_float(pB.y);
        float wC = __int_as_float(pC.y), wD = __int_as_float(pD.y);
        a0 += wA * bf2f(hA.x) + wB * bf2f(hB.x) + wC * bf2f(hC.x) + wD * bf2f(hD.x);
        a1 += wA * bf2f(hA.y) + wB * bf2f(hB.y) + wC * bf2f(hC.y) + wD * bf2f(hD.y);
        a2 += wA * bf2f(hA.z) + wB * bf2f(hB.z) + wC * bf2f(hC.z) + wD * bf2f(hD.z);
        a3 += wA * bf2f(hA.w) + wB * bf2f(hB.w) + wC * bf2f(hC.w) + wD * bf2f(hD.w);
    }
    for (; e < end; e++) {
        int2 p = elist2[e];
        float w = __int_as_float(p.y);
        ushort4 hv = *(const ushort4*)(h1c + (size_t)p.x * ND + lane * 4);
        a0 += w * bf2f(hv.x);
        a1 += w * bf2f(hv.y);
        a2 += w * bf2f(hv.z);
        a3 += w * bf2f(hv.w);
    }
    float4 acc = make_float4(a0, a1, a2, a3);
    ((float4*)(agg2 + (size_t)r * ND))[lane] = acc;
}

// ---- out[j] = log_softmax(dinv[p]*((agg2[r] + dinv[p]*h1[p]) @ W2) + b2) ----
__global__ __launch_bounds__(256) void k_out(
    const int* __restrict__ mpos, const int* __restrict__ mask_map,
    const int* __restrict__ s2c,
    const float* __restrict__ dinv, const unsigned short* __restrict__ h1c,
    const float* __restrict__ agg2, const float* __restrict__ W2,
    const float* __restrict__ b2, float* __restrict__ out) {
    __shared__ float vbuf[16][260];
    __shared__ float dvs[16];
    int t = threadIdx.x;
    int j0 = blockIdx.x * 16;
    for (int r = 0; r < 16; r++) {
        int j = j0 + r;
        int p = mpos[j];
        int rr = mask_map[p];
        int cp = s2c[p];
        float dv = dinv[p];
        vbuf[r][t] = agg2[(size_t)rr * ND + t] + bf2f(h1c[(size_t)cp * ND + t]) * dv;
        if (t == 0) dvs[r] = dv;
    }
    __syncthreads();
    int cq = (t & 63) * 4;
    int rg = t >> 6;
    float acc[4][4] = {};
    for (int k = 0; k < ND; k += 4) {
        float4 w0 = *(const float4*)&W2[(size_t)(k + 0) * ND + cq];
        float4 w1 = *(const float4*)&W2[(size_t)(k + 1) * ND + cq];
        float4 w2 = *(const float4*)&W2[(size_t)(k + 2) * ND + cq];
        float4 w3 = *(const float4*)&W2[(size_t)(k + 3) * ND + cq];
#pragma unroll
        for (int q = 0; q < 4; q++) {
            float4 v = *(const float4*)&vbuf[rg * 4 + q][k];
            acc[q][0] += v.x * w0.x + v.y * w1.x + v.z * w2.x + v.w * w3.x;
            acc[q][1] += v.x * w0.y + v.y * w1.y + v.z * w2.y + v.w * w3.y;
            acc[q][2] += v.x * w0.z + v.y * w1.z + v.z * w2.z + v.w * w3.z;
            acc[q][3] += v.x * w0.w + v.y * w1.w + v.z * w2.w + v.w * w3.w;
        }
    }
    float4 b2v = *(const float4*)&b2[cq];
#pragma unroll
    for (int q = 0; q < 4; q++) {
        int r = rg * 4 + q;
        float dv = dvs[r];
        float l0 = fmaf(dv, acc[q][0], b2v.x);
        float l1 = fmaf(dv, acc[q][1], b2v.y);
        float l2 = fmaf(dv, acc[q][2], b2v.z);
        float l3 = fmaf(dv, acc[q][3], b2v.w);
        float mx = fmaxf(fmaxf(l0, l1), fmaxf(l2, l3));
        for (int o = 32; o >= 1; o >>= 1) mx = fmaxf(mx, __shfl_xor(mx, o, 64));
        float s = __expf(l0 - mx) + __expf(l1 - mx) + __expf(l2 - mx) + __expf(l3 - mx);
        for (int o = 32; o >= 1; o >>= 1) s += __shfl_xor(s, o, 64);
        float lse = mx + __logf(s);
        float4 ov;
        ov.x = l0 - lse; ov.y = l1 - lse; ov.z = l2 - lse; ov.w = l3 - lse;
        *(float4*)&out[(size_t)(j0 + r) * ND + cq] = ov;
    }
}

extern "C" void kernel_launch(void* const* d_in, const int* in_sizes, int n_in,
                              void* d_out, int out_size, void* d_ws, size_t ws_size,
                              hipStream_t stream) {
    const int* x    = (const int*)d_in[0];
    const int* ei   = (const int*)d_in[1];
    const int* src  = ei;
    const int* dst  = ei + NE;
    const int* mpos = (const int*)d_in[2];
    const float* emb = (const float*)d_in[3];
    const float* W1  = (const float*)d_in[4];
    const float* b1  = (const float*)d_in[5];
    const float* W2  = (const float*)d_in[6];
    const float* b2  = (const float*)d_in[7];
    float* out = (float*)d_out;

    char* w = (char*)d_ws;
    size_t o = 0;
    int*   cnt      = (int*)(w + o);   o += (size_t)NN * 4;
    float* dinv     = (float*)(w + o); o += (size_t)NN * 4;
    int*   mask_map = (int*)(w + o);   o += (size_t)NN * 4;
    int*   flag     = (int*)(w + o);   o += (size_t)NN * 4;
    int*   off1     = (int*)(w + o);   o += (size_t)NN * 4;
    int*   cur1     = (int*)(w + o);   o += (size_t)NN * 4;
    int*   nlist    = (int*)(w + o);   o += (size_t)NN * 4;
    int*   s2c      = (int*)(w + o);   o += (size_t)NN * 4;
    int*   cnt2     = (int*)(w + o);   o += (size_t)NM * 4;
    int*   off2     = (int*)(w + o);   o += (size_t)NM * 4;
    int*   cur2     = (int*)(w + o);   o += (size_t)NM * 4;
    int*   nctr     = (int*)(w + o);   o += 64;
    int*   part     = (int*)(w + o);   o += 128 * 4;
    unsigned short* M1 = (unsigned short*)(w + o); o += (size_t)ND * ND * 2;
    int2*  pairs    = (int2*)(w + o);  o += (size_t)NE * 8;            // 6.4 MB
    int2*  elist2   = (int2*)(w + o);  o += (size_t)CAP2 * 8;          // 2 MB
    float* agg2     = (float*)(w + o); o += (size_t)NM * ND * 4;       // 10.24 MB
    unsigned short* h1c = (unsigned short*)(w + o); o += (size_t)NN * ND * 2; // 51.2 MB max

    const int NB1 = (NN + 1023) / 1024;  // 98
    const int NB2 = (NM + 1023) / 1024;  // 10

    hipMemsetAsync(cnt, 0, (size_t)NN * 4, stream);
    hipMemsetAsync(cnt2, 0, (size_t)NM * 4, stream);
    hipMemsetAsync(mask_map, 0xFF, (size_t)NN * 4, stream);  // -1
    hipMemsetAsync(flag, 0, (size_t)NN * 4, stream);
    hipMemsetAsync(nctr, 0, 4, stream);

    k_maskmap<<<(NM + 255) / 256, 256, 0, stream>>>(mpos, mask_map, flag);
    k_edge1<<<(NE + 255) / 256, 256, 0, stream>>>(src, dst, mask_map, cnt, cnt2, flag);
    k_dinv<<<(NN + 255) / 256, 256, 0, stream>>>(cnt, dinv);
    k_compact<<<(NN + 255) / 256, 256, 0, stream>>>(flag, nctr, nlist, s2c);

    // CSR offsets: layer-1 (all nodes; unneeded buckets allocated but unused)
    k_scanA<<<NB1, 256, 0, stream>>>(cnt, part, NN);
    k_scanB<<<1, 64, 0, stream>>>(part, NB1);
    k_scanC<<<NB1, 256, 0, stream>>>(cnt, part, off1, cur1, NN);
    // CSR offsets: layer-2 masked rows
    k_scanA<<<NB2, 256, 0, stream>>>(cnt2, part, NM);
    k_scanB<<<1, 64, 0, stream>>>(part, NB2);
    k_scanC<<<NB2, 256, 0, stream>>>(cnt2, part, off2, cur2, NM);

    k_scat<<<(NE + 255) / 256, 256, 0, stream>>>(src, dst, x, dinv, mask_map, flag,
                                                 s2c, cur1, pairs, cur2, elist2);

    k_m1<<<ND, ND, 0, stream>>>(emb, W1, M1);
    k_expand<<<(NN + 3) / 4, 256, 0, stream>>>(nctr, nlist, x, dinv, off1, cnt,
                                               pairs, M1, b1, h1c);
    k_agg2<<<(NM + 3) / 4, 256, 0, stream>>>(elist2, off2, cnt2, h1c, agg2);
    k_out<<<NM / 16, 256, 0, stream>>>(mpos, mask_map, s2c, dinv, h1c, agg2, W2, b2, out);
}

// Round 4
// 293.711 us; speedup vs baseline: 2.4193x; 1.0307x over previous
//
#include <hip/hip_runtime.h>
#include <hip/hip_bf16.h>
#include <stdint.h>

#define NN 100000   // nodes
#define NE 800000   // edges
#define ND 256      // dim (vocab = node_dim = hidden = 256)
#define NM 10000    // masked outputs
#define NMP 10048   // NM padded to 64-row blocks
#define CAP2 262144 // capacity for masked-edge list (expected ~76k)

typedef __attribute__((ext_vector_type(8))) short bf16x8;
typedef __attribute__((ext_vector_type(4))) float f32x4;

__device__ __forceinline__ float bf2f(unsigned short u) {
    return __uint_as_float(((unsigned)u) << 16);
}
__device__ __forceinline__ unsigned short f2bf(float f) {
    unsigned u = __float_as_uint(f);
    u += 0x7fffu + ((u >> 16) & 1u);   // RNE
    return (unsigned short)(u >> 16);
}

// ---- mask map + flag masked positions as needed ----
__global__ void k_maskmap(const int* __restrict__ mpos, int* __restrict__ mask_map,
                          int* __restrict__ flag) {
    int j = blockIdx.x * 256 + threadIdx.x;
    if (j < NM) { int p = mpos[j]; mask_map[p] = j; flag[p] = 1; }
}

// ---- one edge pass: in-degree, masked-in-edge count, needed-source flag ----
__global__ void k_edge1(const int* __restrict__ src, const int* __restrict__ dst,
                        const int* __restrict__ mask_map,
                        int* __restrict__ cnt, int* __restrict__ cnt2,
                        int* __restrict__ flag) {
    int e = blockIdx.x * 256 + threadIdx.x;
    if (e >= NE) return;
    int d = dst[e];
    atomicAdd(&cnt[d], 1);
    int r = mask_map[d];
    if (r >= 0) {
        atomicAdd(&cnt2[r], 1);
        flag[src[e]] = 1;
    }
}

__global__ void k_dinv(const int* __restrict__ cnt, float* __restrict__ dinv) {
    int i = blockIdx.x * 256 + threadIdx.x;
    if (i < NN) dinv[i] = rsqrtf((float)cnt[i] + 1.0f);
}

// ---- compact needed nodes ----
__global__ void k_compact(const int* __restrict__ flag, int* __restrict__ nctr,
                          int* __restrict__ nlist, int* __restrict__ s2c) {
    int i = blockIdx.x * 256 + threadIdx.x;
    if (i < NN && flag[i]) {
        int c = atomicAdd(nctr, 1);
        nlist[c] = i;
        s2c[i] = c;
    }
}

// ================= 3-phase exclusive scan (CSR offsets) =================
__global__ void k_scanA(const int* __restrict__ cnt, int* __restrict__ part, int n) {
    int b = blockIdx.x, t = threadIdx.x;
    int base = b * 1024 + t * 4;
    int s = 0;
#pragma unroll
    for (int k = 0; k < 4; k++) { int i = base + k; if (i < n) s += cnt[i]; }
    int lane = t & 63, wv = t >> 6;
    int x = s;
    for (int o = 1; o < 64; o <<= 1) { int y = __shfl_up(x, o, 64); if (lane >= o) x += y; }
    __shared__ int ws[4];
    if (lane == 63) ws[wv] = x;
    __syncthreads();
    if (t == 0) part[b] = ws[0] + ws[1] + ws[2] + ws[3];
}

__global__ void k_scanB(int* __restrict__ part, int nb) {
    if (threadIdx.x == 0 && blockIdx.x == 0) {
        int acc = 0;
        for (int i = 0; i < nb; i++) { int v = part[i]; part[i] = acc; acc += v; }
    }
}

__global__ void k_scanC(const int* __restrict__ cnt, const int* __restrict__ part,
                        int* __restrict__ off, int* __restrict__ cur, int n) {
    int b = blockIdx.x, t = threadIdx.x;
    int base = b * 1024 + t * 4;
    int v[4]; int s = 0;
#pragma unroll
    for (int k = 0; k < 4; k++) {
        int i = base + k;
        v[k] = (i < n) ? cnt[i] : 0;
        s += v[k];
    }
    int lane = t & 63, wv = t >> 6;
    int x = s;
    for (int o = 1; o < 64; o <<= 1) { int y = __shfl_up(x, o, 64); if (lane >= o) x += y; }
    __shared__ int ws[4];
    if (lane == 63) ws[wv] = x;
    __syncthreads();
    int add = part[b];
    for (int k = 0; k < wv; k++) add += ws[k];
    int run = add + x - s;
#pragma unroll
    for (int k = 0; k < 4; k++) {
        int i = base + k;
        if (i < n) { off[i] = run; cur[i] = run; }
        run += v[k];
    }
}

// ---- merged scatter: layer-1 pairs (needed dst only) + layer-2 edge list ----
__global__ void k_scat(const int* __restrict__ src, const int* __restrict__ dst,
                       const int* __restrict__ x, const float* __restrict__ dinv,
                       const int* __restrict__ mask_map, const int* __restrict__ flag,
                       const int* __restrict__ s2c,
                       int* __restrict__ cur1, int2* __restrict__ pairs,
                       int* __restrict__ cur2, int2* __restrict__ elist2) {
    int e = blockIdx.x * 256 + threadIdx.x;
    if (e >= NE) return;
    int d = dst[e];
    int f = flag[d];
    int r = mask_map[d];
    if (f == 0 && r < 0) return;
    int s = src[e];
    float w = dinv[s];
    if (f) {
        int pos = atomicAdd(&cur1[d], 1);
        pairs[pos] = make_int2(x[s], __float_as_int(w));
    }
    if (r >= 0) {
        int pos2 = atomicAdd(&cur2[r], 1);
        elist2[pos2] = make_int2(s2c[s], __float_as_int(w));
    }
}

// ---- M1 = emb @ W1, stored bf16 (256x256, L2-resident) ----
__global__ void k_m1(const float* __restrict__ emb, const float* __restrict__ W1,
                     unsigned short* __restrict__ M1) {
    __shared__ float er[ND];
    int v = blockIdx.x, c = threadIdx.x;
    er[c] = emb[v * ND + c];
    __syncthreads();
    float acc = 0.f;
    for (int k = 0; k < ND; k++) acc += er[k] * W1[k * ND + c];
    M1[v * ND + c] = f2bf(acc);
}

// ---- W2t[n][k] = bf16(W2[k][n]) : B^T layout for MFMA ----
__global__ void k_w2t(const float* __restrict__ W2, unsigned short* __restrict__ W2t) {
    int n = blockIdx.x, k = threadIdx.x;
    W2t[n * ND + k] = f2bf(W2[k * ND + n]);
}

// ---- h1c[c] = relu(dinv_i * (sum_e w_e*M1[v_e] + dinv_i*M1[x_i]) + b1), bf16 ----
__global__ void k_expand(const int* __restrict__ nctr, const int* __restrict__ nlist,
                         const int* __restrict__ x, const float* __restrict__ dinv,
                         const int* __restrict__ off1, const int* __restrict__ cnt,
                         const int2* __restrict__ pairs,
                         const unsigned short* __restrict__ M1,
                         const float* __restrict__ b1,
                         unsigned short* __restrict__ h1c) {
    int lane = threadIdx.x & 63;
    int wave = (blockIdx.x * 256 + threadIdx.x) >> 6;
    if (wave >= *nctr) return;
    int i = nlist[wave];
    float4 b1v = ((const float4*)b1)[lane];
    int v0 = x[i];
    float w0 = dinv[i];
    ushort4 mm = *(const ushort4*)(M1 + (size_t)v0 * ND + lane * 4);
    float a0 = w0 * bf2f(mm.x), a1 = w0 * bf2f(mm.y);
    float a2 = w0 * bf2f(mm.z), a3 = w0 * bf2f(mm.w);
    int e = off1[i], end = e + cnt[i];
    for (; e + 4 <= end; e += 4) {
        int2 pA = pairs[e + 0];
        int2 pB = pairs[e + 1];
        int2 pC = pairs[e + 2];
        int2 pD = pairs[e + 3];
        ushort4 mA = *(const ushort4*)(M1 + (size_t)pA.x * ND + lane * 4);
        ushort4 mB = *(const ushort4*)(M1 + (size_t)pB.x * ND + lane * 4);
        ushort4 mC = *(const ushort4*)(M1 + (size_t)pC.x * ND + lane * 4);
        ushort4 mD = *(const ushort4*)(M1 + (size_t)pD.x * ND + lane * 4);
        float wA = __int_as_float(pA.y), wB = __int_as_float(pB.y);
        float wC = __int_as_float(pC.y), wD = __int_as_float(pD.y);
        a0 += wA * bf2f(mA.x) + wB * bf2f(mB.x) + wC * bf2f(mC.x) + wD * bf2f(mD.x);
        a1 += wA * bf2f(mA.y) + wB * bf2f(mB.y) + wC * bf2f(mC.y) + wD * bf2f(mD.y);
        a2 += wA * bf2f(mA.z) + wB * bf2f(mB.z) + wC * bf2f(mC.z) + wD * bf2f(mD.z);
        a3 += wA * bf2f(mA.w) + wB * bf2f(mB.w) + wC * bf2f(mC.w) + wD * bf2f(mD.w);
    }
    for (; e < end; e++) {
        int2 p = pairs[e];
        float w = __int_as_float(p.y);
        ushort4 m2 = *(const ushort4*)(M1 + (size_t)p.x * ND + lane * 4);
        a0 += w * bf2f(m2.x);
        a1 += w * bf2f(m2.y);
        a2 += w * bf2f(m2.z);
        a3 += w * bf2f(m2.w);
    }
    ushort4 o;
    o.x = f2bf(fmaxf(fmaf(w0, a0, b1v.x), 0.f));
    o.y = f2bf(fmaxf(fmaf(w0, a1, b1v.y), 0.f));
    o.z = f2bf(fmaxf(fmaf(w0, a2, b1v.z), 0.f));
    o.w = f2bf(fmaxf(fmaf(w0, a3, b1v.w), 0.f));
    ((ushort4*)(h1c + (size_t)wave * ND))[lane] = o;
}

// ---- layer-2 aggregation (CSR, register acc): agg2[r] = sum w*h1c[cidx] ----
__global__ void k_agg2(const int2* __restrict__ elist2, const int* __restrict__ off2,
                       const int* __restrict__ cnt2,
                       const unsigned short* __restrict__ h1c,
                       float* __restrict__ agg2) {
    int lane = threadIdx.x & 63;
    int wave = (blockIdx.x * 256 + threadIdx.x) >> 6;
    if (wave >= NM) return;
    int r = wave;
    int e = off2[r], end = e + cnt2[r];
    float a0 = 0.f, a1 = 0.f, a2 = 0.f, a3 = 0.f;
    for (; e + 4 <= end; e += 4) {
        int2 pA = elist2[e + 0];
        int2 pB = elist2[e + 1];
        int2 pC = elist2[e + 2];
        int2 pD = elist2[e + 3];
        ushort4 hA = *(const ushort4*)(h1c + (size_t)pA.x * ND + lane * 4);
        ushort4 hB = *(const ushort4*)(h1c + (size_t)pB.x * ND + lane * 4);
        ushort4 hC = *(const ushort4*)(h1c + (size_t)pC.x * ND + lane * 4);
        ushort4 hD = *(const ushort4*)(h1c + (size_t)pD.x * ND + lane * 4);
        float wA = __int_as_float(pA.y), wB = __int_as_float(pB.y);
        float wC = __int_as_float(pC.y), wD = __int_as_float(pD.y);
        a0 += wA * bf2f(hA.x) + wB * bf2f(hB.x) + wC * bf2f(hC.x) + wD * bf2f(hD.x);
        a1 += wA * bf2f(hA.y) + wB * bf2f(hB.y) + wC * bf2f(hC.y) + wD * bf2f(hD.y);
        a2 += wA * bf2f(hA.z) + wB * bf2f(hB.z) + wC * bf2f(hC.z) + wD * bf2f(hD.z);
        a3 += wA * bf2f(hA.w) + wB * bf2f(hB.w) + wC * bf2f(hC.w) + wD * bf2f(hD.w);
    }
    for (; e < end; e++) {
        int2 p = elist2[e];
        float w = __int_as_float(p.y);
        ushort4 hv = *(const ushort4*)(h1c + (size_t)p.x * ND + lane * 4);
        a0 += w * bf2f(hv.x);
        a1 += w * bf2f(hv.y);
        a2 += w * bf2f(hv.z);
        a3 += w * bf2f(hv.w);
    }
    float4 acc = make_float4(a0, a1, a2, a3);
    ((float4*)(agg2 + (size_t)r * ND))[lane] = acc;
}

// ---- vb[j][k] = bf16( dv*agg2[rr][k] + dv^2*h1c[cp][k] ), rows >= NM zeroed ----
__global__ void k_vrows(const int* __restrict__ mpos, const int* __restrict__ mask_map,
                        const int* __restrict__ s2c, const float* __restrict__ dinv,
                        const unsigned short* __restrict__ h1c,
                        const float* __restrict__ agg2,
                        unsigned short* __restrict__ vb) {
    int lane = threadIdx.x & 63;
    int wave = (blockIdx.x * 256 + threadIdx.x) >> 6;   // row j
    if (wave >= NMP) return;
    ushort4 o;
    if (wave >= NM) {
        o.x = o.y = o.z = o.w = 0;
    } else {
        int p = mpos[wave];
        int rr = mask_map[p];
        int cp = s2c[p];
        float dv = dinv[p];
        float dv2 = dv * dv;
        float4 ag = ((const float4*)(agg2 + (size_t)rr * ND))[lane];
        ushort4 hv = ((const ushort4*)(h1c + (size_t)cp * ND))[lane];
        o.x = f2bf(fmaf(dv2, bf2f(hv.x), dv * ag.x));
        o.y = f2bf(fmaf(dv2, bf2f(hv.y), dv * ag.y));
        o.z = f2bf(fmaf(dv2, bf2f(hv.z), dv * ag.z));
        o.w = f2bf(fmaf(dv2, bf2f(hv.w), dv * ag.w));
    }
    ((ushort4*)(vb + (size_t)wave * ND))[lane] = o;
}

// ---- MFMA GEMM + log-softmax: out[j] = log_softmax(vb[j] @ W2 + b2) ----
__global__ __launch_bounds__(256) void k_out2(
    const unsigned short* __restrict__ vb, const unsigned short* __restrict__ W2t,
    const float* __restrict__ b2, float* __restrict__ out) {
    int lane = threadIdx.x & 63;
    int wv = threadIdx.x >> 6;
    int row0 = blockIdx.x * 64 + wv * 16;   // 16 rows per wave
    int qm = lane & 15, qk = lane >> 4;
    // preload A fragments: A[m=qm][k=qk*8+j] per k-step
    bf16x8 afr[8];
    const unsigned short* arow = vb + (size_t)(row0 + qm) * ND + qk * 8;
#pragma unroll
    for (int kt = 0; kt < 8; kt++) afr[kt] = *(const bf16x8*)(arow + kt * 32);
    f32x4 acc[16];
#pragma unroll
    for (int t = 0; t < 16; t++) acc[t] = (f32x4){0.f, 0.f, 0.f, 0.f};
#pragma unroll
    for (int t = 0; t < 16; t++) {
        const unsigned short* brow = W2t + (size_t)(t * 16 + qm) * ND + qk * 8;
#pragma unroll
        for (int kt = 0; kt < 8; kt++) {
            bf16x8 bfr = *(const bf16x8*)(brow + kt * 32);
            acc[t] = __builtin_amdgcn_mfma_f32_16x16x32_bf16(afr[kt], bfr, acc[t], 0, 0, 0);
        }
    }
    // lane holds rows m = qk*4+r (r=0..3), cols qm+16t. Add b2, log-softmax per row.
    float mx[4] = {-1e30f, -1e30f, -1e30f, -1e30f};
#pragma unroll
    for (int t = 0; t < 16; t++) {
        float cb = b2[qm + 16 * t];
#pragma unroll
        for (int r = 0; r < 4; r++) {
            float v = acc[t][r] + cb;
            acc[t][r] = v;
            mx[r] = fmaxf(mx[r], v);
        }
    }
#pragma unroll
    for (int r = 0; r < 4; r++)
        for (int o = 1; o < 16; o <<= 1) mx[r] = fmaxf(mx[r], __shfl_xor(mx[r], o, 64));
    float sm[4] = {0.f, 0.f, 0.f, 0.f};
#pragma unroll
    for (int t = 0; t < 16; t++)
#pragma unroll
        for (int r = 0; r < 4; r++) sm[r] += __expf(acc[t][r] - mx[r]);
#pragma unroll
    for (int r = 0; r < 4; r++)
        for (int o = 1; o < 16; o <<= 1) sm[r] += __shfl_xor(sm[r], o, 64);
#pragma unroll
    for (int r = 0; r < 4; r++) {
        int row = row0 + qk * 4 + r;
        if (row >= NM) continue;
        float lse = mx[r] + __logf(sm[r]);
        float* orow = out + (size_t)row * ND + qm;
#pragma unroll
        for (int t = 0; t < 16; t++) orow[16 * t] = acc[t][r] - lse;
    }
}

extern "C" void kernel_launch(void* const* d_in, const int* in_sizes, int n_in,
                              void* d_out, int out_size, void* d_ws, size_t ws_size,
                              hipStream_t stream) {
    const int* x    = (const int*)d_in[0];
    const int* ei   = (const int*)d_in[1];
    const int* src  = ei;
    const int* dst  = ei + NE;
    const int* mpos = (const int*)d_in[2];
    const float* emb = (const float*)d_in[3];
    const float* W1  = (const float*)d_in[4];
    const float* b1  = (const float*)d_in[5];
    const float* W2  = (const float*)d_in[6];
    const float* b2  = (const float*)d_in[7];
    float* out = (float*)d_out;

    char* w = (char*)d_ws;
    size_t o = 0;
    int*   cnt      = (int*)(w + o);   o += (size_t)NN * 4;
    float* dinv     = (float*)(w + o); o += (size_t)NN * 4;
    int*   mask_map = (int*)(w + o);   o += (size_t)NN * 4;
    int*   flag     = (int*)(w + o);   o += (size_t)NN * 4;
    int*   off1     = (int*)(w + o);   o += (size_t)NN * 4;
    int*   cur1     = (int*)(w + o);   o += (size_t)NN * 4;
    int*   nlist    = (int*)(w + o);   o += (size_t)NN * 4;
    int*   s2c      = (int*)(w + o);   o += (size_t)NN * 4;
    int*   cnt2     = (int*)(w + o);   o += (size_t)NM * 4;
    int*   off2     = (int*)(w + o);   o += (size_t)NM * 4;
    int*   cur2     = (int*)(w + o);   o += (size_t)NM * 4;
    int*   nctr     = (int*)(w + o);   o += 64;
    int*   part     = (int*)(w + o);   o += 128 * 4;
    unsigned short* M1  = (unsigned short*)(w + o); o += (size_t)ND * ND * 2;
    unsigned short* W2t = (unsigned short*)(w + o); o += (size_t)ND * ND * 2;
    unsigned short* vb  = (unsigned short*)(w + o); o += (size_t)NMP * ND * 2; // 5.1 MB
    int2*  pairs    = (int2*)(w + o);  o += (size_t)NE * 8;            // 6.4 MB
    int2*  elist2   = (int2*)(w + o);  o += (size_t)CAP2 * 8;          // 2 MB
    float* agg2     = (float*)(w + o); o += (size_t)NM * ND * 4;       // 10.24 MB
    unsigned short* h1c = (unsigned short*)(w + o); o += (size_t)NN * ND * 2; // 51.2 MB max

    const int NB1 = (NN + 1023) / 1024;  // 98
    const int NB2 = (NM + 1023) / 1024;  // 10

    hipMemsetAsync(cnt, 0, (size_t)NN * 4, stream);
    hipMemsetAsync(cnt2, 0, (size_t)NM * 4, stream);
    hipMemsetAsync(mask_map, 0xFF, (size_t)NN * 4, stream);  // -1
    hipMemsetAsync(flag, 0, (size_t)NN * 4, stream);
    hipMemsetAsync(nctr, 0, 4, stream);

    k_maskmap<<<(NM + 255) / 256, 256, 0, stream>>>(mpos, mask_map, flag);
    k_edge1<<<(NE + 255) / 256, 256, 0, stream>>>(src, dst, mask_map, cnt, cnt2, flag);
    k_dinv<<<(NN + 255) / 256, 256, 0, stream>>>(cnt, dinv);
    k_compact<<<(NN + 255) / 256, 256, 0, stream>>>(flag, nctr, nlist, s2c);

    // CSR offsets: layer-1 (all nodes) and layer-2 masked rows
    k_scanA<<<NB1, 256, 0, stream>>>(cnt, part, NN);
    k_scanB<<<1, 64, 0, stream>>>(part, NB1);
    k_scanC<<<NB1, 256, 0, stream>>>(cnt, part, off1, cur1, NN);
    k_scanA<<<NB2, 256, 0, stream>>>(cnt2, part, NM);
    k_scanB<<<1, 64, 0, stream>>>(part, NB2);
    k_scanC<<<NB2, 256, 0, stream>>>(cnt2, part, off2, cur2, NM);

    k_scat<<<(NE + 255) / 256, 256, 0, stream>>>(src, dst, x, dinv, mask_map, flag,
                                                 s2c, cur1, pairs, cur2, elist2);

    k_m1<<<ND, ND, 0, stream>>>(emb, W1, M1);
    k_w2t<<<ND, ND, 0, stream>>>(W2, W2t);
    k_expand<<<(NN + 3) / 4, 256, 0, stream>>>(nctr, nlist, x, dinv, off1, cnt,
                                               pairs, M1, b1, h1c);
    k_agg2<<<(NM + 3) / 4, 256, 0, stream>>>(elist2, off2, cnt2, h1c, agg2);
    k_vrows<<<NMP / 4, 256, 0, stream>>>(mpos, mask_map, s2c, dinv, h1c, agg2, vb);
    k_out2<<<NMP / 64, 256, 0, stream>>>(vb, W2t, b2, out);
}

// Round 5
// 251.241 us; speedup vs baseline: 2.8283x; 1.1690x over previous
//
#include <hip/hip_runtime.h>
#include <stdint.h>

#define NN 100000            // nodes
#define NE 800000            // edges
#define ND 256               // dim (vocab = node_dim = hidden = 256)
#define NM 10000             // masked outputs
#define NMP 10048            // NM padded to 64-row blocks
#define NTOT (NN + NM)       // unified count/offset array length
#define NTB ((NTOT + 1023) / 1024)   // scan blocks = 108

typedef __attribute__((ext_vector_type(8))) short bf16x8;
typedef __attribute__((ext_vector_type(4))) float f32x4;

__device__ __forceinline__ float bf2f(unsigned short u) {
    return __uint_as_float(((unsigned)u) << 16);
}
__device__ __forceinline__ unsigned short f2bf(float f) {
    unsigned u = __float_as_uint(f);
    u += 0x7fffu + ((u >> 16) & 1u);   // RNE
    return (unsigned short)(u >> 16);
}

// info[i] encoding: bit0 = "h1 needed"; (info>>1)-1 = masked row index (or -1 if info<2)

__global__ void k_init(int* __restrict__ carr, int* __restrict__ info,
                       int* __restrict__ nctr) {
    int i = blockIdx.x * 256 + threadIdx.x;
    if (i < NTOT) carr[i] = 0;
    if (i < NN) info[i] = 0;
    if (i == 0) *nctr = 0;
}

__global__ void k_maskmap(const int* __restrict__ mpos, int* __restrict__ info) {
    int j = blockIdx.x * 256 + threadIdx.x;
    if (j < NM) info[mpos[j]] = ((j + 1) << 1) | 1;  // duplicate p: any winner
}

// one edge pass: in-degree, masked-row in-edge count, needed-source flag
__global__ void k_edge1(const int* __restrict__ src, const int* __restrict__ dst,
                        int* __restrict__ info, int* __restrict__ carr) {
    int e = blockIdx.x * 256 + threadIdx.x;
    if (e >= NE) return;
    int d = dst[e];
    atomicAdd(&carr[d], 1);
    int ii = info[d];
    if (ii > 1) {
        int r = (ii >> 1) - 1;
        atomicAdd(&carr[NN + r], 1);
        atomicOr(&info[src[e]], 1);
    }
}

// scan phase A (block partials) fused with per-node work: dinv, xd pack, compaction
__global__ void k_scanA(const int* __restrict__ carr, int* __restrict__ part,
                        const int* __restrict__ x, const int* __restrict__ info,
                        float* __restrict__ dinv, int2* __restrict__ xd,
                        int* __restrict__ nctr, int* __restrict__ nlist,
                        int* __restrict__ s2c) {
    int b = blockIdx.x, t = threadIdx.x;
    int base = b * 1024 + t * 4;
    int s = 0;
#pragma unroll
    for (int k = 0; k < 4; k++) {
        int i = base + k;
        if (i < NTOT) {
            int c = carr[i];
            s += c;
            if (i < NN) {
                float dv = rsqrtf((float)c + 1.0f);
                dinv[i] = dv;
                xd[i] = make_int2(x[i], __float_as_int(dv));
                if (info[i] & 1) {
                    int cc = atomicAdd(nctr, 1);
                    nlist[cc] = i;
                    s2c[i] = cc;
                }
            }
        }
    }
    int lane = t & 63, wv = t >> 6;
    int xx = s;
    for (int o = 1; o < 64; o <<= 1) { int y = __shfl_up(xx, o, 64); if (lane >= o) xx += y; }
    __shared__ int ws[4];
    if (lane == 63) ws[wv] = xx;
    __syncthreads();
    if (t == 0) part[b] = ws[0] + ws[1] + ws[2] + ws[3];
}

// scan phase B: exclusive scan of block partials (nb <= 128), one block
__global__ void k_scanB(int* __restrict__ part, int nb) {
    int t = threadIdx.x;
    int v = (t < nb) ? part[t] : 0;
    int lane = t & 63, wv = t >> 6;
    int xx = v;
    for (int o = 1; o < 64; o <<= 1) { int y = __shfl_up(xx, o, 64); if (lane >= o) xx += y; }
    __shared__ int ws[2];
    if (lane == 63) ws[wv] = xx;
    __syncthreads();
    int add = (wv == 1) ? ws[0] : 0;
    if (t < nb) part[t] = add + xx - v;
}

__global__ void k_scanC(const int* __restrict__ carr, const int* __restrict__ part,
                        int* __restrict__ off, int* __restrict__ cur) {
    int b = blockIdx.x, t = threadIdx.x;
    int base = b * 1024 + t * 4;
    int v[4]; int s = 0;
#pragma unroll
    for (int k = 0; k < 4; k++) {
        int i = base + k;
        v[k] = (i < NTOT) ? carr[i] : 0;
        s += v[k];
    }
    int lane = t & 63, wv = t >> 6;
    int xx = s;
    for (int o = 1; o < 64; o <<= 1) { int y = __shfl_up(xx, o, 64); if (lane >= o) xx += y; }
    __shared__ int ws[4];
    if (lane == 63) ws[wv] = xx;
    __syncthreads();
    int add = part[b];
    for (int k = 0; k < wv; k++) add += ws[k];
    int run = add + xx - s;
#pragma unroll
    for (int k = 0; k < 4; k++) {
        int i = base + k;
        if (i < NTOT) { off[i] = run; cur[i] = run; }
        run += v[k];
    }
}

// merged scatter: layer-1 pairs (needed dst) + layer-2 list (masked dst), one buffer
__global__ void k_scat(const int* __restrict__ src, const int* __restrict__ dst,
                       const int* __restrict__ info, const int2* __restrict__ xd,
                       const int* __restrict__ s2c, int* __restrict__ cur,
                       int2* __restrict__ pairs) {
    int e = blockIdx.x * 256 + threadIdx.x;
    if (e >= NE) return;
    int d = dst[e];
    int ii = info[d];
    if (ii == 0) return;
    int s = src[e];
    int2 xv = xd[s];
    if (ii & 1) {
        int pos = atomicAdd(&cur[d], 1);
        pairs[pos] = xv;                                  // (vocab, dinv) of src
    }
    if (ii > 1) {
        int r = (ii >> 1) - 1;
        int pos2 = atomicAdd(&cur[NN + r], 1);
        pairs[pos2] = make_int2(s2c[s], xv.y);            // (compact idx, dinv)
    }
}

// M1 = bf16(emb @ W1) [blocks 0..255]; W2t[n][k] = bf16(W2[k][n]) [blocks 256..511]
__global__ void k_m1w2t(const float* __restrict__ emb, const float* __restrict__ W1,
                        const float* __restrict__ W2,
                        unsigned short* __restrict__ M1, unsigned short* __restrict__ W2t) {
    __shared__ float er[ND];
    int b = blockIdx.x, c = threadIdx.x;
    if (b < ND) {
        er[c] = emb[b * ND + c];
        __syncthreads();
        float acc = 0.f;
        for (int k = 0; k < ND; k++) acc += er[k] * W1[k * ND + c];
        M1[b * ND + c] = f2bf(acc);
    } else {
        int n = b - ND;
        W2t[n * ND + c] = f2bf(W2[c * ND + n]);
    }
}

// h1c[cc] = bf16(relu(dv_i*(sum_e w_e*M1[v_e] + dv_i*M1[x_i]) + b1))
__global__ void k_expand(const int* __restrict__ nctr, const int* __restrict__ nlist,
                         const int2* __restrict__ xd,
                         const int* __restrict__ off, const int* __restrict__ carr,
                         const int2* __restrict__ pairs,
                         const unsigned short* __restrict__ M1,
                         const float* __restrict__ b1,
                         unsigned short* __restrict__ h1c) {
    int lane = threadIdx.x & 63;
    int wave = (blockIdx.x * 256 + threadIdx.x) >> 6;
    if (wave >= *nctr) return;
    int i = nlist[wave];
    float4 b1v = ((const float4*)b1)[lane];
    int2 x0 = xd[i];
    int v0 = x0.x;
    float w0 = __int_as_float(x0.y);
    ushort4 mm = *(const ushort4*)(M1 + (size_t)v0 * ND + lane * 4);
    float a0 = w0 * bf2f(mm.x), a1 = w0 * bf2f(mm.y);
    float a2 = w0 * bf2f(mm.z), a3 = w0 * bf2f(mm.w);
    int e = off[i], end = e + carr[i];
    for (; e + 4 <= end; e += 4) {
        int2 pA = pairs[e + 0];
        int2 pB = pairs[e + 1];
        int2 pC = pairs[e + 2];
        int2 pD = pairs[e + 3];
        ushort4 mA = *(const ushort4*)(M1 + (size_t)pA.x * ND + lane * 4);
        ushort4 mB = *(const ushort4*)(M1 + (size_t)pB.x * ND + lane * 4);
        ushort4 mC = *(const ushort4*)(M1 + (size_t)pC.x * ND + lane * 4);
        ushort4 mD = *(const ushort4*)(M1 + (size_t)pD.x * ND + lane * 4);
        float wA = __int_as_float(pA.y), wB = __int_as_float(pB.y);
        float wC = __int_as_float(pC.y), wD = __int_as_float(pD.y);
        a0 += wA * bf2f(mA.x) + wB * bf2f(mB.x) + wC * bf2f(mC.x) + wD * bf2f(mD.x);
        a1 += wA * bf2f(mA.y) + wB * bf2f(mB.y) + wC * bf2f(mC.y) + wD * bf2f(mD.y);
        a2 += wA * bf2f(mA.z) + wB * bf2f(mB.z) + wC * bf2f(mC.z) + wD * bf2f(mD.z);
        a3 += wA * bf2f(mA.w) + wB * bf2f(mB.w) + wC * bf2f(mC.w) + wD * bf2f(mD.w);
    }
    for (; e < end; e++) {
        int2 p = pairs[e];
        float w = __int_as_float(p.y);
        ushort4 m2 = *(const ushort4*)(M1 + (size_t)p.x * ND + lane * 4);
        a0 += w * bf2f(m2.x);
        a1 += w * bf2f(m2.y);
        a2 += w * bf2f(m2.z);
        a3 += w * bf2f(m2.w);
    }
    ushort4 o;
    o.x = f2bf(fmaxf(fmaf(w0, a0, b1v.x), 0.f));
    o.y = f2bf(fmaxf(fmaf(w0, a1, b1v.y), 0.f));
    o.z = f2bf(fmaxf(fmaf(w0, a2, b1v.z), 0.f));
    o.w = f2bf(fmaxf(fmaf(w0, a3, b1v.w), 0.f));
    ((ushort4*)(h1c + (size_t)wave * ND))[lane] = o;
}

// layer-2 aggregation + self-loop + dv scale, bf16 out:
// agg2b[r] = bf16( dv * (sum_e w_e*h1c[ce] + dv*h1c[cp]) )   (A-matrix rows for k_out2)
__global__ void k_agg2(const int* __restrict__ mpos, const int* __restrict__ info,
                       const int* __restrict__ s2c, const float* __restrict__ dinv,
                       const int2* __restrict__ pairs, const int* __restrict__ off,
                       const int* __restrict__ carr,
                       const unsigned short* __restrict__ h1c,
                       unsigned short* __restrict__ agg2b) {
    int lane = threadIdx.x & 63;
    int wave = (blockIdx.x * 256 + threadIdx.x) >> 6;
    if (wave >= NM) return;
    int r = wave;
    int p = mpos[r];
    if (((info[p] >> 1) - 1) != r) return;   // duplicate mask position: not representative
    int cp = s2c[p];
    float dv = dinv[p];
    // self-loop term: dv * h1c[cp]
    ushort4 h0 = *(const ushort4*)(h1c + (size_t)cp * ND + lane * 4);
    float a0 = dv * bf2f(h0.x), a1 = dv * bf2f(h0.y);
    float a2 = dv * bf2f(h0.z), a3 = dv * bf2f(h0.w);
    int e = off[NN + r], end = e + carr[NN + r];
    for (; e + 4 <= end; e += 4) {
        int2 pA = pairs[e + 0];
        int2 pB = pairs[e + 1];
        int2 pC = pairs[e + 2];
        int2 pD = pairs[e + 3];
        ushort4 hA = *(const ushort4*)(h1c + (size_t)pA.x * ND + lane * 4);
        ushort4 hB = *(const ushort4*)(h1c + (size_t)pB.x * ND + lane * 4);
        ushort4 hC = *(const ushort4*)(h1c + (size_t)pC.x * ND + lane * 4);
        ushort4 hD = *(const ushort4*)(h1c + (size_t)pD.x * ND + lane * 4);
        float wA = __int_as_float(pA.y), wB = __int_as_float(pB.y);
        float wC = __int_as_float(pC.y), wD = __int_as_float(pD.y);
        a0 += wA * bf2f(hA.x) + wB * bf2f(hB.x) + wC * bf2f(hC.x) + wD * bf2f(hD.x);
        a1 += wA * bf2f(hA.y) + wB * bf2f(hB.y) + wC * bf2f(hC.y) + wD * bf2f(hD.y);
        a2 += wA * bf2f(hA.z) + wB * bf2f(hB.z) + wC * bf2f(hC.z) + wD * bf2f(hD.z);
        a3 += wA * bf2f(hA.w) + wB * bf2f(hB.w) + wC * bf2f(hC.w) + wD * bf2f(hD.w);
    }
    for (; e < end; e++) {
        int2 pp = pairs[e];
        float w = __int_as_float(pp.y);
        ushort4 hv = *(const ushort4*)(h1c + (size_t)pp.x * ND + lane * 4);
        a0 += w * bf2f(hv.x);
        a1 += w * bf2f(hv.y);
        a2 += w * bf2f(hv.z);
        a3 += w * bf2f(hv.w);
    }
    ushort4 o;
    o.x = f2bf(dv * a0);
    o.y = f2bf(dv * a1);
    o.z = f2bf(dv * a2);
    o.w = f2bf(dv * a3);
    ((ushort4*)(agg2b + (size_t)r * ND))[lane] = o;
}

// MFMA GEMM + log-softmax: out[j] = log_softmax(agg2b[rep(j)] @ W2 + b2)
__global__ __launch_bounds__(256) void k_out2(
    const int* __restrict__ mpos, const int* __restrict__ info,
    const unsigned short* __restrict__ agg2b, const unsigned short* __restrict__ W2t,
    const float* __restrict__ b2, float* __restrict__ out) {
    int lane = threadIdx.x & 63;
    int wv = threadIdx.x >> 6;
    int row0 = blockIdx.x * 64 + wv * 16;   // 16 rows per wave
    int qm = lane & 15, qk = lane >> 4;
    int row = row0 + qm;
    bf16x8 afr[8];
    if (row < NM) {
        int p = mpos[row];
        int rr = (info[p] >> 1) - 1;
        const unsigned short* arow = agg2b + (size_t)rr * ND + qk * 8;
#pragma unroll
        for (int kt = 0; kt < 8; kt++) afr[kt] = *(const bf16x8*)(arow + kt * 32);
    } else {
#pragma unroll
        for (int kt = 0; kt < 8; kt++) afr[kt] = (bf16x8){0, 0, 0, 0, 0, 0, 0, 0};
    }
    f32x4 acc[16];
#pragma unroll
    for (int t = 0; t < 16; t++) acc[t] = (f32x4){0.f, 0.f, 0.f, 0.f};
#pragma unroll
    for (int t = 0; t < 16; t++) {
        const unsigned short* brow = W2t + (size_t)(t * 16 + qm) * ND + qk * 8;
#pragma unroll
        for (int kt = 0; kt < 8; kt++) {
            bf16x8 bfr = *(const bf16x8*)(brow + kt * 32);
            acc[t] = __builtin_amdgcn_mfma_f32_16x16x32_bf16(afr[kt], bfr, acc[t], 0, 0, 0);
        }
    }
    // lane holds rows m = qk*4+r (r=0..3), cols qm+16t
    float mx[4] = {-1e30f, -1e30f, -1e30f, -1e30f};
#pragma unroll
    for (int t = 0; t < 16; t++) {
        float cb = b2[qm + 16 * t];
#pragma unroll
        for (int r = 0; r < 4; r++) {
            float v = acc[t][r] + cb;
            acc[t][r] = v;
            mx[r] = fmaxf(mx[r], v);
        }
    }
#pragma unroll
    for (int r = 0; r < 4; r++)
        for (int o = 1; o < 16; o <<= 1) mx[r] = fmaxf(mx[r], __shfl_xor(mx[r], o, 64));
    float sm[4] = {0.f, 0.f, 0.f, 0.f};
#pragma unroll
    for (int t = 0; t < 16; t++)
#pragma unroll
        for (int r = 0; r < 4; r++) sm[r] += __expf(acc[t][r] - mx[r]);
#pragma unroll
    for (int r = 0; r < 4; r++)
        for (int o = 1; o < 16; o <<= 1) sm[r] += __shfl_xor(sm[r], o, 64);
#pragma unroll
    for (int r = 0; r < 4; r++) {
        int orow_i = row0 + qk * 4 + r;
        if (orow_i >= NM) continue;
        float lse = mx[r] + __logf(sm[r]);
        float* orow = out + (size_t)orow_i * ND + qm;
#pragma unroll
        for (int t = 0; t < 16; t++) orow[16 * t] = acc[t][r] - lse;
    }
}

extern "C" void kernel_launch(void* const* d_in, const int* in_sizes, int n_in,
                              void* d_out, int out_size, void* d_ws, size_t ws_size,
                              hipStream_t stream) {
    const int* x    = (const int*)d_in[0];
    const int* ei   = (const int*)d_in[1];
    const int* src  = ei;
    const int* dst  = ei + NE;
    const int* mpos = (const int*)d_in[2];
    const float* emb = (const float*)d_in[3];
    const float* W1  = (const float*)d_in[4];
    const float* b1  = (const float*)d_in[5];
    const float* W2  = (const float*)d_in[6];
    const float* b2  = (const float*)d_in[7];
    float* out = (float*)d_out;

    char* w = (char*)d_ws;
    size_t o = 0;
    int*   carr  = (int*)(w + o);  o += (size_t)(NTOT + 64) * 4;
    int*   off   = (int*)(w + o);  o += (size_t)(NTOT + 64) * 4;
    int*   cur   = (int*)(w + o);  o += (size_t)(NTOT + 64) * 4;
    int*   info  = (int*)(w + o);  o += (size_t)NN * 4;
    float* dinv  = (float*)(w + o); o += (size_t)NN * 4;
    int2*  xd    = (int2*)(w + o); o += (size_t)NN * 8;
    int*   nlist = (int*)(w + o);  o += (size_t)NN * 4;
    int*   s2c   = (int*)(w + o);  o += (size_t)NN * 4;
    int*   nctr  = (int*)(w + o);  o += 64;
    int*   part  = (int*)(w + o);  o += 128 * 4;
    unsigned short* M1    = (unsigned short*)(w + o); o += (size_t)ND * ND * 2;
    unsigned short* W2t   = (unsigned short*)(w + o); o += (size_t)ND * ND * 2;
    unsigned short* agg2b = (unsigned short*)(w + o); o += (size_t)NM * ND * 2;  // 5.1 MB
    int2*  pairs = (int2*)(w + o); o += (size_t)NE * 2 * 8;                      // 12.8 MB
    unsigned short* h1c  = (unsigned short*)(w + o); o += (size_t)NN * ND * 2;   // 51.2 MB

    k_init<<<(NTOT + 255) / 256, 256, 0, stream>>>(carr, info, nctr);
    k_maskmap<<<(NM + 255) / 256, 256, 0, stream>>>(mpos, info);
    k_edge1<<<(NE + 255) / 256, 256, 0, stream>>>(src, dst, info, carr);
    k_scanA<<<NTB, 256, 0, stream>>>(carr, part, x, info, dinv, xd, nctr, nlist, s2c);
    k_scanB<<<1, 128, 0, stream>>>(part, NTB);
    k_scanC<<<NTB, 256, 0, stream>>>(carr, part, off, cur);
    k_scat<<<(NE + 255) / 256, 256, 0, stream>>>(src, dst, info, xd, s2c, cur, pairs);
    k_m1w2t<<<2 * ND, ND, 0, stream>>>(emb, W1, W2, M1, W2t);
    k_expand<<<(NN + 3) / 4, 256, 0, stream>>>(nctr, nlist, xd, off, carr, pairs, M1, b1, h1c);
    k_agg2<<<(NM + 3) / 4, 256, 0, stream>>>(mpos, info, s2c, dinv, pairs, off, carr, h1c, agg2b);
    k_out2<<<NMP / 64, 256, 0, stream>>>(mpos, info, agg2b, W2t, b2, out);
}